// Round 1
// baseline (639.053 us; speedup 1.0000x reference)
//
#include <hip/hip_runtime.h>
#include <math.h>

// ---------------------------------------------------------------------------
// Attention: B=4, S=2048, E=1024, H=8, O=128 (fp32 in/out)
// Strategy: split-bf16 (hi+lo) MFMA for x->QK and QK^T (precision-critical),
// plain bf16 MFMA for V / PV / ctx@Wo. Flash-attention (no S x S materialize).
// ---------------------------------------------------------------------------

typedef __attribute__((ext_vector_type(8))) short bf16x8;   // 8 bf16 (4 VGPRs)
typedef __attribute__((ext_vector_type(4))) float f32x4;

#define MFMA(a, b, c) __builtin_amdgcn_mfma_f32_16x16x32_bf16((a), (b), (c), 0, 0, 0)

__device__ __forceinline__ short f2bf(float f) {
    union { float f; unsigned u; } v; v.f = f;
    unsigned r = v.u + 0x7fffu + ((v.u >> 16) & 1u);   // RNE
    return (short)(r >> 16);
}
__device__ __forceinline__ float bf2f(short s) {
    union { unsigned u; float f; } v; v.u = ((unsigned)(unsigned short)s) << 16;
    return v.f;
}

// ---------------- prep kernels ----------------

__global__ __launch_bounds__(256) void split_kernel(
    const float* __restrict__ x, short* __restrict__ hi, short* __restrict__ lo, int n) {
    for (int i = blockIdx.x * blockDim.x + threadIdx.x; i < n; i += gridDim.x * blockDim.x) {
        float f = x[i];
        short h = f2bf(f);
        hi[i] = h;
        lo[i] = f2bf(f - bf2f(h));
    }
}

// Wt[n][k] (1280 x 1024): n<1024 -> Wq[h=n>>7][k][o=n&127]; [1024,1152) -> Wk[k][n-1024];
// [1152,1280) -> Wv[k][n-1152]. Split hi/lo.
__global__ __launch_bounds__(256) void build_wt(
    const float* __restrict__ Wq, const float* __restrict__ Wk, const float* __restrict__ Wv,
    short* __restrict__ wth, short* __restrict__ wtl) {
    const int total = 1280 * 1024;
    for (int idx = blockIdx.x * blockDim.x + threadIdx.x; idx < total; idx += gridDim.x * blockDim.x) {
        int n = idx >> 10, k = idx & 1023;
        float f;
        if (n < 1024)      f = Wq[((size_t)(n >> 7) * 1024 + k) * 128 + (n & 127)];
        else if (n < 1152) f = Wk[(size_t)k * 128 + (n - 1024)];
        else               f = Wv[(size_t)k * 128 + (n - 1152)];
        short h = f2bf(f);
        wth[idx] = h;
        wtl[idx] = f2bf(f - bf2f(h));
    }
}

// wot[e][k] = Wo[k][e]  (1024 x 1024), bf16
__global__ __launch_bounds__(256) void build_wot(
    const float* __restrict__ Wo, short* __restrict__ wot) {
    const int total = 1024 * 1024;
    for (int idx = blockIdx.x * blockDim.x + threadIdx.x; idx < total; idx += gridDim.x * blockDim.x) {
        int e = idx >> 10, k = idx & 1023;
        wot[idx] = f2bf(Wo[(size_t)k * 1024 + e]);
    }
}

// ---------------- GEMM: C(M x N) = A(M x 1024) @ Bt(N x 1024)^T ----------------
// MODE 0: split A/B (3 passes), epilogue scatters Q(hi/lo, BHSD), K(hi/lo, BSD), Vt(B,D,S)
// MODE 1: single bf16, epilogue writes fp32 to outf (M=8192, N=1024)
template <int MODE>
__global__ __launch_bounds__(256, 2) void gemm_k(
    const short* __restrict__ Ah, const short* __restrict__ Al,
    const short* __restrict__ Bth, const short* __restrict__ Btl,
    short* __restrict__ qh, short* __restrict__ ql,
    short* __restrict__ kh, short* __restrict__ kl,
    short* __restrict__ vt, float* __restrict__ outf) {
    constexpr int K = 1024;
    constexpr int LDA = 40;  // 32 + 8 pad (bf16) -> 2-way-max LDS bank aliasing
    __shared__ short As_h[128 * LDA];
    __shared__ short Bs_h[128 * LDA];
    __shared__ short As_l[(MODE == 0 ? 128 : 1) * LDA];
    __shared__ short Bs_l[(MODE == 0 ? 128 : 1) * LDA];

    const int t = threadIdx.x;
    const int m0 = blockIdx.x * 128, n0 = blockIdx.y * 128;
    const int wave = t >> 6, lane = t & 63;
    const int wr = wave >> 1, wc = wave & 1;
    const int quad = lane >> 4, l16 = lane & 15;

    f32x4 acc[4][4];
    for (int i = 0; i < 4; ++i)
        for (int j = 0; j < 4; ++j) acc[i][j] = (f32x4){0.f, 0.f, 0.f, 0.f};

    for (int kb = 0; kb < K / 32; ++kb) {
        __syncthreads();
        // stage 128x32 tiles: 512 x 16B units per matrix; 2 units/thread
        for (int pp = 0; pp < 2; ++pp) {
            int u = t + pp * 256;
            int row = u >> 2, c = u & 3;
            size_t ga = (size_t)(m0 + row) * K + kb * 32 + c * 8;
            size_t gb = (size_t)(n0 + row) * K + kb * 32 + c * 8;
            int ls = row * LDA + c * 8;
            *(bf16x8*)&As_h[ls] = *(const bf16x8*)(Ah + ga);
            *(bf16x8*)&Bs_h[ls] = *(const bf16x8*)(Bth + gb);
            if constexpr (MODE == 0) {
                *(bf16x8*)&As_l[ls] = *(const bf16x8*)(Al + ga);
                *(bf16x8*)&Bs_l[ls] = *(const bf16x8*)(Btl + gb);
            }
        }
        __syncthreads();

        bf16x8 a[4], b[4];
        for (int mi = 0; mi < 4; ++mi)
            a[mi] = *(const bf16x8*)&As_h[(wr * 64 + mi * 16 + l16) * LDA + quad * 8];
        for (int ni = 0; ni < 4; ++ni)
            b[ni] = *(const bf16x8*)&Bs_h[(wc * 64 + ni * 16 + l16) * LDA + quad * 8];
        for (int mi = 0; mi < 4; ++mi)
            for (int ni = 0; ni < 4; ++ni)
                acc[mi][ni] = MFMA(a[mi], b[ni], acc[mi][ni]);
        if constexpr (MODE == 0) {
            bf16x8 al[4], bl[4];
            for (int mi = 0; mi < 4; ++mi)
                al[mi] = *(const bf16x8*)&As_l[(wr * 64 + mi * 16 + l16) * LDA + quad * 8];
            for (int ni = 0; ni < 4; ++ni)
                bl[ni] = *(const bf16x8*)&Bs_l[(wc * 64 + ni * 16 + l16) * LDA + quad * 8];
            for (int mi = 0; mi < 4; ++mi)
                for (int ni = 0; ni < 4; ++ni) {
                    acc[mi][ni] = MFMA(a[mi], bl[ni], acc[mi][ni]);
                    acc[mi][ni] = MFMA(al[mi], b[ni], acc[mi][ni]);
                }
        }
    }

    // epilogue: C/D layout col = l16, row = quad*4 + r  [m89/m91-verified]
    for (int mi = 0; mi < 4; ++mi) {
        int rowb = m0 + wr * 64 + mi * 16 + quad * 4;
        for (int ni = 0; ni < 4; ++ni) {
            int col = n0 + wc * 64 + ni * 16 + l16;
            for (int r = 0; r < 4; ++r) {
                float v = acc[mi][ni][r];
                int row = rowb + r;
                if constexpr (MODE == 1) {
                    outf[(size_t)row * 1024 + col] = v;
                } else {
                    int bb = row >> 11, s = row & 2047;
                    short hv = f2bf(v);
                    short lv = f2bf(v - bf2f(hv));
                    if (col < 1024) {
                        size_t qi = (((size_t)(bb * 8 + (col >> 7))) * 2048 + s) * 128 + (col & 127);
                        qh[qi] = hv; ql[qi] = lv;
                    } else if (col < 1152) {
                        size_t ki = ((size_t)bb * 2048 + s) * 128 + (col - 1024);
                        kh[ki] = hv; kl[ki] = lv;
                    } else {
                        size_t vi = ((size_t)bb * 128 + (col - 1152)) * 2048 + s;
                        vt[vi] = hv;
                    }
                }
            }
        }
    }
}

// ---------------- flash attention ----------------
// grid (S/64, B*H); 4 waves x 16 query rows; BN=64 keys/iter; D=128.
__global__ __launch_bounds__(256, 2) void attn_k(
    const short* __restrict__ qh, const short* __restrict__ ql,
    const short* __restrict__ kh, const short* __restrict__ kl,
    const short* __restrict__ vt, short* __restrict__ ctx) {
    constexpr int S = 2048, D = 128;
    __shared__ short Kh_s[64 * 136];   // key rows, stride 128+8
    __shared__ short Kl_s[64 * 136];
    __shared__ short Vt_s[128 * 72];   // V^T: rows = o, stride 64+8
    __shared__ short P_s[4 * 16 * 72]; // per-wave P (16 q x 64 k), stride 64+8

    const int bh = blockIdx.y, b = bh >> 3, h = bh & 7;
    const int q0 = blockIdx.x * 64;
    const int t = threadIdx.x, wave = t >> 6, lane = t & 63;
    const int quad = lane >> 4, l16 = lane & 15;

    // Q fragments: A-layout A[m=l16][k=quad*8+j], 4 chunks of K=32 over D=128
    bf16x8 qfh[4], qfl[4];
    {
        size_t qbase = ((size_t)(b * 8 + h) * S + q0 + wave * 16 + l16) * D + quad * 8;
        for (int c = 0; c < 4; ++c) {
            qfh[c] = *(const bf16x8*)(qh + qbase + c * 32);
            qfl[c] = *(const bf16x8*)(ql + qbase + c * 32);
        }
    }

    float mrow[4], lrow[4];
    f32x4 oacc[8];
    for (int r = 0; r < 4; ++r) { mrow[r] = -INFINITY; lrow[r] = 0.f; }
    for (int oi = 0; oi < 8; ++oi) oacc[oi] = (f32x4){0.f, 0.f, 0.f, 0.f};

    const float scale = 0.08838834764831845f;  // 1/sqrt(128)

    for (int kt = 0; kt < S / 64; ++kt) {
        __syncthreads();  // protect LDS reuse from previous iteration
        // stage K hi/lo: 64 rows x 128 -> 1024 x 16B units
        for (int pp = 0; pp < 4; ++pp) {
            int u = t + pp * 256, row = u >> 4, c = u & 15;
            size_t g = ((size_t)b * S + kt * 64 + row) * D + c * 8;
            int ls = row * 136 + c * 8;
            *(bf16x8*)&Kh_s[ls] = *(const bf16x8*)(kh + g);
            *(bf16x8*)&Kl_s[ls] = *(const bf16x8*)(kl + g);
        }
        // stage V^T: 128 rows x 64 -> 1024 x 16B units (vt global is (B,D,S))
        for (int pp = 0; pp < 4; ++pp) {
            int u = t + pp * 256, row = u >> 3, c = u & 7;
            size_t g = ((size_t)b * D + row) * S + kt * 64 + c * 8;
            *(bf16x8*)&Vt_s[row * 72 + c * 8] = *(const bf16x8*)(vt + g);
        }
        __syncthreads();

        // S = Q K^T (split: hh + lh + hl)
        f32x4 sacc[4];
        for (int ni = 0; ni < 4; ++ni) sacc[ni] = (f32x4){0.f, 0.f, 0.f, 0.f};
        for (int c = 0; c < 4; ++c) {
            for (int ni = 0; ni < 4; ++ni) {
                int base = (ni * 16 + l16) * 136 + c * 32 + quad * 8;
                bf16x8 kbh = *(const bf16x8*)&Kh_s[base];
                bf16x8 kbl = *(const bf16x8*)&Kl_s[base];
                sacc[ni] = MFMA(qfh[c], kbh, sacc[ni]);
                sacc[ni] = MFMA(qfl[c], kbh, sacc[ni]);
                sacc[ni] = MFMA(qfh[c], kbl, sacc[ni]);
            }
        }

        // online softmax; lane holds rows quad*4+r, key col ni*16+l16
        float mnew[4], alpha[4];
        for (int r = 0; r < 4; ++r) {
            float mx = -INFINITY;
            for (int ni = 0; ni < 4; ++ni) {
                sacc[ni][r] *= scale;
                mx = fmaxf(mx, sacc[ni][r]);
            }
            for (int off = 8; off; off >>= 1) mx = fmaxf(mx, __shfl_xor(mx, off));
            mnew[r] = fmaxf(mrow[r], mx);
            alpha[r] = __expf(mrow[r] - mnew[r]);
            mrow[r] = mnew[r];
            float rs = 0.f;
            for (int ni = 0; ni < 4; ++ni) {
                float pv = __expf(sacc[ni][r] - mnew[r]);
                sacc[ni][r] = pv;
                rs += pv;
            }
            for (int off = 8; off; off >>= 1) rs += __shfl_xor(rs, off);
            lrow[r] = lrow[r] * alpha[r] + rs;
        }

        // P -> LDS (C-layout -> A-layout transform; per-wave slice, in-wave ordered)
        for (int ni = 0; ni < 4; ++ni)
            for (int r = 0; r < 4; ++r)
                P_s[(wave * 16 + quad * 4 + r) * 72 + ni * 16 + l16] = f2bf(sacc[ni][r]);

        // rescale running O
        for (int oi = 0; oi < 8; ++oi)
            for (int r = 0; r < 4; ++r) oacc[oi][r] *= alpha[r];

        // O += P @ V  (A = P[m=l16][kk], B = Vt[kk][o])
        for (int c2 = 0; c2 < 2; ++c2) {
            bf16x8 pa = *(const bf16x8*)&P_s[(wave * 16 + l16) * 72 + c2 * 32 + quad * 8];
            for (int oi = 0; oi < 8; ++oi) {
                bf16x8 vb = *(const bf16x8*)&Vt_s[(oi * 16 + l16) * 72 + c2 * 32 + quad * 8];
                oacc[oi] = MFMA(pa, vb, oacc[oi]);
            }
        }
    }

    // epilogue: ctx[b][s][h*128+o] bf16
    for (int r = 0; r < 4; ++r) {
        float inv = 1.f / lrow[r];
        int s = q0 + wave * 16 + quad * 4 + r;
        size_t base = ((size_t)b * S + s) * 1024 + h * 128;
        for (int oi = 0; oi < 8; ++oi)
            ctx[base + oi * 16 + l16] = f2bf(oacc[oi][r] * inv);
    }
}

// ---------------- launch ----------------

extern "C" void kernel_launch(void* const* d_in, const int* in_sizes, int n_in,
                              void* d_out, int out_size, void* d_ws, size_t ws_size,
                              hipStream_t stream) {
    const float* x  = (const float*)d_in[0];
    const float* Wq = (const float*)d_in[1];
    const float* Wk = (const float*)d_in[2];
    const float* Wv = (const float*)d_in[3];
    const float* Wo = (const float*)d_in[4];
    float* out = (float*)d_out;

    char* p = (char*)d_ws;
    auto alloc = [&](size_t bytes) { char* r = p; p += bytes; return r; };
    short* xh  = (short*)alloc(16777216);  // x hi    (8192 x 1024)
    short* xl  = (short*)alloc(16777216);  // x lo
    short* wth = (short*)alloc(2621440);   // Wt hi   (1280 x 1024)
    short* wtl = (short*)alloc(2621440);   // Wt lo
    short* wot = (short*)alloc(2097152);   // Wo^T    (1024 x 1024)
    short* qh  = (short*)alloc(16777216);  // Q hi    (B,H,S,D)
    short* ql  = (short*)alloc(16777216);  // Q lo
    short* kh  = (short*)alloc(2097152);   // K hi    (B,S,D)
    short* kl  = (short*)alloc(2097152);   // K lo
    short* vt  = (short*)alloc(2097152);   // V^T     (B,D,S)
    short* ctx = (short*)alloc(16777216);  // ctx     (B,S,H*D)

    split_kernel<<<dim3(2048), dim3(256), 0, stream>>>(x, xh, xl, 8192 * 1024);
    build_wt<<<dim3(1280), dim3(256), 0, stream>>>(Wq, Wk, Wv, wth, wtl);
    build_wot<<<dim3(1024), dim3(256), 0, stream>>>(Wo, wot);
    gemm_k<0><<<dim3(64, 10), dim3(256), 0, stream>>>(xh, xl, wth, wtl,
                                                      qh, ql, kh, kl, vt, nullptr);
    attn_k<<<dim3(32, 32), dim3(256), 0, stream>>>(qh, ql, kh, kl, vt, ctx);
    gemm_k<1><<<dim3(64, 8), dim3(256), 0, stream>>>(ctx, nullptr, wot, nullptr,
                                                     nullptr, nullptr, nullptr, nullptr,
                                                     nullptr, out);
}

// Round 2
// 442.507 us; speedup vs baseline: 1.4442x; 1.4442x over previous
//
#include <hip/hip_runtime.h>
#include <math.h>

// ---------------------------------------------------------------------------
// Attention: B=4, S=2048, E=1024, H=8, O=128 (fp32 in/out)
// Strategy: split-bf16 (hi+lo) MFMA for x->QK and QK^T (precision-critical),
// plain bf16 MFMA for V / PV / ctx@Wo. Flash-attention (no S x S materialize).
// R1 change: GEMM epilogue staged through LDS -> coalesced 16B stores
// (was: scalar 2B scatter stores causing 29x HBM write amplification).
// ---------------------------------------------------------------------------

typedef __attribute__((ext_vector_type(8))) short bf16x8;   // 8 bf16 (4 VGPRs)
typedef __attribute__((ext_vector_type(4))) float f32x4;

#define MFMA(a, b, c) __builtin_amdgcn_mfma_f32_16x16x32_bf16((a), (b), (c), 0, 0, 0)

__device__ __forceinline__ short f2bf(float f) {
    union { float f; unsigned u; } v; v.f = f;
    unsigned r = v.u + 0x7fffu + ((v.u >> 16) & 1u);   // RNE
    return (short)(r >> 16);
}
__device__ __forceinline__ float bf2f(short s) {
    union { unsigned u; float f; } v; v.u = ((unsigned)(unsigned short)s) << 16;
    return v.f;
}

// ---------------- prep kernels ----------------

__global__ __launch_bounds__(256) void split_kernel(
    const float* __restrict__ x, short* __restrict__ hi, short* __restrict__ lo, int n) {
    for (int i = blockIdx.x * blockDim.x + threadIdx.x; i < n; i += gridDim.x * blockDim.x) {
        float f = x[i];
        short h = f2bf(f);
        hi[i] = h;
        lo[i] = f2bf(f - bf2f(h));
    }
}

// Wt[n][k] (1280 x 1024): n<1024 -> Wq[h=n>>7][k][o=n&127]; [1024,1152) -> Wk[k][n-1024];
// [1152,1280) -> Wv[k][n-1152]. Split hi/lo.
__global__ __launch_bounds__(256) void build_wt(
    const float* __restrict__ Wq, const float* __restrict__ Wk, const float* __restrict__ Wv,
    short* __restrict__ wth, short* __restrict__ wtl) {
    const int total = 1280 * 1024;
    for (int idx = blockIdx.x * blockDim.x + threadIdx.x; idx < total; idx += gridDim.x * blockDim.x) {
        int n = idx >> 10, k = idx & 1023;
        float f;
        if (n < 1024)      f = Wq[((size_t)(n >> 7) * 1024 + k) * 128 + (n & 127)];
        else if (n < 1152) f = Wk[(size_t)k * 128 + (n - 1024)];
        else               f = Wv[(size_t)k * 128 + (n - 1152)];
        short h = f2bf(f);
        wth[idx] = h;
        wtl[idx] = f2bf(f - bf2f(h));
    }
}

// wot[e][k] = Wo[k][e]  (1024 x 1024), bf16
__global__ __launch_bounds__(256) void build_wot(
    const float* __restrict__ Wo, short* __restrict__ wot) {
    const int total = 1024 * 1024;
    for (int idx = blockIdx.x * blockDim.x + threadIdx.x; idx < total; idx += gridDim.x * blockDim.x) {
        int e = idx >> 10, k = idx & 1023;
        wot[idx] = f2bf(Wo[(size_t)k * 1024 + e]);
    }
}

// ---------------- GEMM: C(M x N) = A(M x 1024) @ Bt(N x 1024)^T ----------------
// MODE 0: split A/B (3 passes). N=1280 = [8 x 128 Q | 128 K | 128 V] so each
//         128-col block has a uniform destination: y<8 -> Q(h=y), y==8 -> K,
//         y==9 -> V^T. Epilogue stages the tile in LDS (hi|lo packed u32,
//         2 passes of 64 rows) then emits coalesced 16B stores.
// MODE 1: single bf16, fp32 out (M=8192, N=1024), LDS-staged float4 stores.
template <int MODE>
__global__ __launch_bounds__(256, 2) void gemm_k(
    const short* __restrict__ Ah, const short* __restrict__ Al,
    const short* __restrict__ Bth, const short* __restrict__ Btl,
    short* __restrict__ qh, short* __restrict__ ql,
    short* __restrict__ kh, short* __restrict__ kl,
    short* __restrict__ vt, float* __restrict__ outf) {
    constexpr int K = 1024;
    constexpr int LDA = 40;  // 32 + 8 pad (bf16) -> 2-way-max LDS bank aliasing
    __shared__ short As_h[128 * LDA];
    __shared__ short Bs_h[128 * LDA];
    __shared__ short As_l[(MODE == 0 ? 128 : 1) * LDA];
    __shared__ short Bs_l[(MODE == 0 ? 128 : 1) * LDA];
    __shared__ unsigned int Ep[64 * 132];  // epilogue staging: 64 rows x (128+4) pad

    const int t = threadIdx.x;
    const int m0 = blockIdx.x * 128, n0 = blockIdx.y * 128;
    const int wave = t >> 6, lane = t & 63;
    const int wr = wave >> 1, wc = wave & 1;
    const int quad = lane >> 4, l16 = lane & 15;

    f32x4 acc[4][4];
    for (int i = 0; i < 4; ++i)
        for (int j = 0; j < 4; ++j) acc[i][j] = (f32x4){0.f, 0.f, 0.f, 0.f};

    for (int kb = 0; kb < K / 32; ++kb) {
        __syncthreads();
        // stage 128x32 tiles: 512 x 16B units per matrix; 2 units/thread
        for (int pp = 0; pp < 2; ++pp) {
            int u = t + pp * 256;
            int row = u >> 2, c = u & 3;
            size_t ga = (size_t)(m0 + row) * K + kb * 32 + c * 8;
            size_t gb = (size_t)(n0 + row) * K + kb * 32 + c * 8;
            int ls = row * LDA + c * 8;
            *(bf16x8*)&As_h[ls] = *(const bf16x8*)(Ah + ga);
            *(bf16x8*)&Bs_h[ls] = *(const bf16x8*)(Bth + gb);
            if constexpr (MODE == 0) {
                *(bf16x8*)&As_l[ls] = *(const bf16x8*)(Al + ga);
                *(bf16x8*)&Bs_l[ls] = *(const bf16x8*)(Btl + gb);
            }
        }
        __syncthreads();

        bf16x8 a[4], b[4];
        for (int mi = 0; mi < 4; ++mi)
            a[mi] = *(const bf16x8*)&As_h[(wr * 64 + mi * 16 + l16) * LDA + quad * 8];
        for (int ni = 0; ni < 4; ++ni)
            b[ni] = *(const bf16x8*)&Bs_h[(wc * 64 + ni * 16 + l16) * LDA + quad * 8];
        for (int mi = 0; mi < 4; ++mi)
            for (int ni = 0; ni < 4; ++ni)
                acc[mi][ni] = MFMA(a[mi], b[ni], acc[mi][ni]);
        if constexpr (MODE == 0) {
            bf16x8 al[4], bl[4];
            for (int mi = 0; mi < 4; ++mi)
                al[mi] = *(const bf16x8*)&As_l[(wr * 64 + mi * 16 + l16) * LDA + quad * 8];
            for (int ni = 0; ni < 4; ++ni)
                bl[ni] = *(const bf16x8*)&Bs_l[(wc * 64 + ni * 16 + l16) * LDA + quad * 8];
            for (int mi = 0; mi < 4; ++mi)
                for (int ni = 0; ni < 4; ++ni) {
                    acc[mi][ni] = MFMA(a[mi], bl[ni], acc[mi][ni]);
                    acc[mi][ni] = MFMA(al[mi], b[ni], acc[mi][ni]);
                }
        }
    }

    // ---------------- LDS-staged epilogue ----------------
    // C/D layout: col = l16, row = quad*4 + r  [m89/m91-verified]
    // Two passes of 64 rows; waves with wr==p own pass-p rows.
    for (int p = 0; p < 2; ++p) {
        __syncthreads();
        if (wr == p) {
            for (int mi = 0; mi < 4; ++mi) {
                int rl = mi * 16 + quad * 4;  // local row base within the 64-row pass
                for (int ni = 0; ni < 4; ++ni) {
                    int cl = wc * 64 + ni * 16 + l16;
                    for (int r = 0; r < 4; ++r) {
                        float v = acc[mi][ni][r];
                        unsigned pk;
                        if constexpr (MODE == 0) {
                            short hv = f2bf(v);
                            short lv = f2bf(v - bf2f(hv));
                            pk = (unsigned)(unsigned short)hv |
                                 ((unsigned)(unsigned short)lv << 16);
                        } else {
                            union { float f; unsigned u; } cv; cv.f = v; pk = cv.u;
                        }
                        Ep[(rl + r) * 132 + cl] = pk;
                    }
                }
            }
        }
        __syncthreads();

        if constexpr (MODE == 1) {
            // 64 rows x 128 fp32 -> float4 stores; 8 chunks/thread
            for (int j = 0; j < 8; ++j) {
                int cid = t + j * 256;
                int row = cid >> 5, c = cid & 31;
                f32x4 val;
                for (int q = 0; q < 4; ++q) {
                    union { unsigned u; float f; } cv;
                    cv.u = Ep[row * 132 + c * 4 + q];
                    val[q] = cv.f;
                }
                int gr = m0 + p * 64 + row;
                *(f32x4*)&outf[(size_t)gr * 1024 + n0 + c * 4] = val;
            }
        } else if (blockIdx.y < 9) {
            // Q (y<8) or K (y==8): dest is d-contiguous; row-wise 16B stores
            for (int j = 0; j < 4; ++j) {
                int cid = t + j * 256;
                int row = cid >> 4, c = cid & 15;
                bf16x8 hv, lv;
                for (int q = 0; q < 8; ++q) {
                    unsigned w = Ep[row * 132 + c * 8 + q];
                    hv[q] = (short)(w & 0xffffu);
                    lv[q] = (short)(w >> 16);
                }
                int gr = m0 + p * 64 + row;
                int bb = gr >> 11, s = gr & 2047;
                if (blockIdx.y < 8) {
                    size_t base = (((size_t)(bb * 8 + (n0 >> 7))) * 2048 + s) * 128 + c * 8;
                    *(bf16x8*)&qh[base] = hv;
                    *(bf16x8*)&ql[base] = lv;
                } else {
                    size_t base = ((size_t)bb * 2048 + s) * 128 + c * 8;
                    *(bf16x8*)&kh[base] = hv;
                    *(bf16x8*)&kl[base] = lv;
                }
            }
        } else {
            // V -> vt (B,D,S): column reads (stride 132 words -> bank stride 4,
            // conflict-free across the 8-row group), s-contiguous 16B stores
            for (int j = 0; j < 4; ++j) {
                int cid = t + j * 256;
                int d = cid >> 3, sc = cid & 7;
                bf16x8 hv;
                for (int q = 0; q < 8; ++q) {
                    unsigned w = Ep[(sc * 8 + q) * 132 + d];
                    hv[q] = (short)(w & 0xffffu);
                }
                int gr0 = m0 + p * 64 + sc * 8;
                int bb = gr0 >> 11, s0 = gr0 & 2047;
                *(bf16x8*)&vt[((size_t)bb * 128 + d) * 2048 + s0] = hv;
            }
        }
    }
}

// ---------------- flash attention ----------------
// grid (S/64, B*H); 4 waves x 16 query rows; BN=64 keys/iter; D=128.
__global__ __launch_bounds__(256, 2) void attn_k(
    const short* __restrict__ qh, const short* __restrict__ ql,
    const short* __restrict__ kh, const short* __restrict__ kl,
    const short* __restrict__ vt, short* __restrict__ ctx) {
    constexpr int S = 2048, D = 128;
    __shared__ short Kh_s[64 * 136];   // key rows, stride 128+8
    __shared__ short Kl_s[64 * 136];
    __shared__ short Vt_s[128 * 72];   // V^T: rows = o, stride 64+8
    __shared__ short P_s[4 * 16 * 72]; // per-wave P (16 q x 64 k), stride 64+8

    const int bh = blockIdx.y, b = bh >> 3, h = bh & 7;
    const int q0 = blockIdx.x * 64;
    const int t = threadIdx.x, wave = t >> 6, lane = t & 63;
    const int quad = lane >> 4, l16 = lane & 15;

    // Q fragments: A-layout A[m=l16][k=quad*8+j], 4 chunks of K=32 over D=128
    bf16x8 qfh[4], qfl[4];
    {
        size_t qbase = ((size_t)(b * 8 + h) * S + q0 + wave * 16 + l16) * D + quad * 8;
        for (int c = 0; c < 4; ++c) {
            qfh[c] = *(const bf16x8*)(qh + qbase + c * 32);
            qfl[c] = *(const bf16x8*)(ql + qbase + c * 32);
        }
    }

    float mrow[4], lrow[4];
    f32x4 oacc[8];
    for (int r = 0; r < 4; ++r) { mrow[r] = -INFINITY; lrow[r] = 0.f; }
    for (int oi = 0; oi < 8; ++oi) oacc[oi] = (f32x4){0.f, 0.f, 0.f, 0.f};

    const float scale = 0.08838834764831845f;  // 1/sqrt(128)

    for (int kt = 0; kt < S / 64; ++kt) {
        __syncthreads();  // protect LDS reuse from previous iteration
        // stage K hi/lo: 64 rows x 128 -> 1024 x 16B units
        for (int pp = 0; pp < 4; ++pp) {
            int u = t + pp * 256, row = u >> 4, c = u & 15;
            size_t g = ((size_t)b * S + kt * 64 + row) * D + c * 8;
            int ls = row * 136 + c * 8;
            *(bf16x8*)&Kh_s[ls] = *(const bf16x8*)(kh + g);
            *(bf16x8*)&Kl_s[ls] = *(const bf16x8*)(kl + g);
        }
        // stage V^T: 128 rows x 64 -> 1024 x 16B units (vt global is (B,D,S))
        for (int pp = 0; pp < 4; ++pp) {
            int u = t + pp * 256, row = u >> 3, c = u & 7;
            size_t g = ((size_t)b * D + row) * S + kt * 64 + c * 8;
            *(bf16x8*)&Vt_s[row * 72 + c * 8] = *(const bf16x8*)(vt + g);
        }
        __syncthreads();

        // S = Q K^T (split: hh + lh + hl)
        f32x4 sacc[4];
        for (int ni = 0; ni < 4; ++ni) sacc[ni] = (f32x4){0.f, 0.f, 0.f, 0.f};
        for (int c = 0; c < 4; ++c) {
            for (int ni = 0; ni < 4; ++ni) {
                int base = (ni * 16 + l16) * 136 + c * 32 + quad * 8;
                bf16x8 kbh = *(const bf16x8*)&Kh_s[base];
                bf16x8 kbl = *(const bf16x8*)&Kl_s[base];
                sacc[ni] = MFMA(qfh[c], kbh, sacc[ni]);
                sacc[ni] = MFMA(qfl[c], kbh, sacc[ni]);
                sacc[ni] = MFMA(qfh[c], kbl, sacc[ni]);
            }
        }

        // online softmax; lane holds rows quad*4+r, key col ni*16+l16
        float mnew[4], alpha[4];
        for (int r = 0; r < 4; ++r) {
            float mx = -INFINITY;
            for (int ni = 0; ni < 4; ++ni) {
                sacc[ni][r] *= scale;
                mx = fmaxf(mx, sacc[ni][r]);
            }
            for (int off = 8; off; off >>= 1) mx = fmaxf(mx, __shfl_xor(mx, off));
            mnew[r] = fmaxf(mrow[r], mx);
            alpha[r] = __expf(mrow[r] - mnew[r]);
            mrow[r] = mnew[r];
            float rs = 0.f;
            for (int ni = 0; ni < 4; ++ni) {
                float pv = __expf(sacc[ni][r] - mnew[r]);
                sacc[ni][r] = pv;
                rs += pv;
            }
            for (int off = 8; off; off >>= 1) rs += __shfl_xor(rs, off);
            lrow[r] = lrow[r] * alpha[r] + rs;
        }

        // P -> LDS (C-layout -> A-layout transform; per-wave slice, in-wave ordered)
        for (int ni = 0; ni < 4; ++ni)
            for (int r = 0; r < 4; ++r)
                P_s[(wave * 16 + quad * 4 + r) * 72 + ni * 16 + l16] = f2bf(sacc[ni][r]);

        // rescale running O
        for (int oi = 0; oi < 8; ++oi)
            for (int r = 0; r < 4; ++r) oacc[oi][r] *= alpha[r];

        // O += P @ V  (A = P[m=l16][kk], B = Vt[kk][o])
        for (int c2 = 0; c2 < 2; ++c2) {
            bf16x8 pa = *(const bf16x8*)&P_s[(wave * 16 + l16) * 72 + c2 * 32 + quad * 8];
            for (int oi = 0; oi < 8; ++oi) {
                bf16x8 vb = *(const bf16x8*)&Vt_s[(oi * 16 + l16) * 72 + c2 * 32 + quad * 8];
                oacc[oi] = MFMA(pa, vb, oacc[oi]);
            }
        }
    }

    // epilogue: ctx[b][s][h*128+o] bf16
    for (int r = 0; r < 4; ++r) {
        float inv = 1.f / lrow[r];
        int s = q0 + wave * 16 + quad * 4 + r;
        size_t base = ((size_t)b * S + s) * 1024 + h * 128;
        for (int oi = 0; oi < 8; ++oi)
            ctx[base + oi * 16 + l16] = f2bf(oacc[oi][r] * inv);
    }
}

// ---------------- launch ----------------

extern "C" void kernel_launch(void* const* d_in, const int* in_sizes, int n_in,
                              void* d_out, int out_size, void* d_ws, size_t ws_size,
                              hipStream_t stream) {
    const float* x  = (const float*)d_in[0];
    const float* Wq = (const float*)d_in[1];
    const float* Wk = (const float*)d_in[2];
    const float* Wv = (const float*)d_in[3];
    const float* Wo = (const float*)d_in[4];
    float* out = (float*)d_out;

    char* p = (char*)d_ws;
    auto alloc = [&](size_t bytes) { char* r = p; p += bytes; return r; };
    short* xh  = (short*)alloc(16777216);  // x hi    (8192 x 1024)
    short* xl  = (short*)alloc(16777216);  // x lo
    short* wth = (short*)alloc(2621440);   // Wt hi   (1280 x 1024)
    short* wtl = (short*)alloc(2621440);   // Wt lo
    short* wot = (short*)alloc(2097152);   // Wo^T    (1024 x 1024)
    short* qh  = (short*)alloc(16777216);  // Q hi    (B,H,S,D)
    short* ql  = (short*)alloc(16777216);  // Q lo
    short* kh  = (short*)alloc(2097152);   // K hi    (B,S,D)
    short* kl  = (short*)alloc(2097152);   // K lo
    short* vt  = (short*)alloc(2097152);   // V^T     (B,D,S)
    short* ctx = (short*)alloc(16777216);  // ctx     (B,S,H*D)

    split_kernel<<<dim3(2048), dim3(256), 0, stream>>>(x, xh, xl, 8192 * 1024);
    build_wt<<<dim3(1280), dim3(256), 0, stream>>>(Wq, Wk, Wv, wth, wtl);
    build_wot<<<dim3(1024), dim3(256), 0, stream>>>(Wo, wot);
    gemm_k<0><<<dim3(64, 10), dim3(256), 0, stream>>>(xh, xl, wth, wtl,
                                                      qh, ql, kh, kl, vt, nullptr);
    attn_k<<<dim3(32, 32), dim3(256), 0, stream>>>(qh, ql, kh, kl, vt, ctx);
    gemm_k<1><<<dim3(64, 8), dim3(256), 0, stream>>>(ctx, nullptr, wot, nullptr,
                                                     nullptr, nullptr, nullptr, nullptr,
                                                     nullptr, out);
}

// Round 3
// 405.867 us; speedup vs baseline: 1.5745x; 1.0903x over previous
//
#include <hip/hip_runtime.h>
#include <math.h>

// ---------------------------------------------------------------------------
// Attention: B=4, S=2048, E=1024, H=8, O=128 (fp32 in/out)
// Split-bf16 (hi+lo) MFMA for x->QK and QK^T (precision-critical), plain bf16
// for V / PV / ctx@Wo. Flash-attention (no S x S materialize).
// R1: GEMM epilogue staged through LDS -> coalesced stores.
// R2: attn restructured: BM=128 (32 q-rows/wave -> 2x LDS-read reuse),
//     global_load_lds staging with XOR-swizzled chunk layout (conflict-free,
//     no VGPR roundtrip). attn was DS-pipe bound (50 b128/wave-iter for 64
//     MFMA; 2.6e7 bank-conflict cycles).
// ---------------------------------------------------------------------------

typedef __attribute__((ext_vector_type(8))) short bf16x8;   // 8 bf16 (4 VGPRs)
typedef __attribute__((ext_vector_type(4))) float f32x4;

#define MFMA(a, b, c) __builtin_amdgcn_mfma_f32_16x16x32_bf16((a), (b), (c), 0, 0, 0)
#define GLB(p) ((const __attribute__((address_space(1))) void*)(p))
#define LDS(p) ((__attribute__((address_space(3))) void*)(p))

__device__ __forceinline__ short f2bf(float f) {
    union { float f; unsigned u; } v; v.f = f;
    unsigned r = v.u + 0x7fffu + ((v.u >> 16) & 1u);   // RNE
    return (short)(r >> 16);
}
__device__ __forceinline__ float bf2f(short s) {
    union { unsigned u; float f; } v; v.u = ((unsigned)(unsigned short)s) << 16;
    return v.f;
}

// ---------------- prep kernels ----------------

__global__ __launch_bounds__(256) void split_kernel(
    const float* __restrict__ x, short* __restrict__ hi, short* __restrict__ lo, int n) {
    for (int i = blockIdx.x * blockDim.x + threadIdx.x; i < n; i += gridDim.x * blockDim.x) {
        float f = x[i];
        short h = f2bf(f);
        hi[i] = h;
        lo[i] = f2bf(f - bf2f(h));
    }
}

__global__ __launch_bounds__(256) void build_wt(
    const float* __restrict__ Wq, const float* __restrict__ Wk, const float* __restrict__ Wv,
    short* __restrict__ wth, short* __restrict__ wtl) {
    const int total = 1280 * 1024;
    for (int idx = blockIdx.x * blockDim.x + threadIdx.x; idx < total; idx += gridDim.x * blockDim.x) {
        int n = idx >> 10, k = idx & 1023;
        float f;
        if (n < 1024)      f = Wq[((size_t)(n >> 7) * 1024 + k) * 128 + (n & 127)];
        else if (n < 1152) f = Wk[(size_t)k * 128 + (n - 1024)];
        else               f = Wv[(size_t)k * 128 + (n - 1152)];
        short h = f2bf(f);
        wth[idx] = h;
        wtl[idx] = f2bf(f - bf2f(h));
    }
}

__global__ __launch_bounds__(256) void build_wot(
    const float* __restrict__ Wo, short* __restrict__ wot) {
    const int total = 1024 * 1024;
    for (int idx = blockIdx.x * blockDim.x + threadIdx.x; idx < total; idx += gridDim.x * blockDim.x) {
        int e = idx >> 10, k = idx & 1023;
        wot[idx] = f2bf(Wo[(size_t)k * 1024 + e]);
    }
}

// ---------------- GEMM: C(M x N) = A(M x 1024) @ Bt(N x 1024)^T ----------------
template <int MODE>
__global__ __launch_bounds__(256, 2) void gemm_k(
    const short* __restrict__ Ah, const short* __restrict__ Al,
    const short* __restrict__ Bth, const short* __restrict__ Btl,
    short* __restrict__ qh, short* __restrict__ ql,
    short* __restrict__ kh, short* __restrict__ kl,
    short* __restrict__ vt, float* __restrict__ outf) {
    constexpr int K = 1024;
    constexpr int LDA = 40;  // 32 + 8 pad (bf16)
    __shared__ short As_h[128 * LDA];
    __shared__ short Bs_h[128 * LDA];
    __shared__ short As_l[(MODE == 0 ? 128 : 1) * LDA];
    __shared__ short Bs_l[(MODE == 0 ? 128 : 1) * LDA];
    __shared__ unsigned int Ep[64 * 132];  // epilogue staging

    const int t = threadIdx.x;
    const int m0 = blockIdx.x * 128, n0 = blockIdx.y * 128;
    const int wave = t >> 6, lane = t & 63;
    const int wr = wave >> 1, wc = wave & 1;
    const int quad = lane >> 4, l16 = lane & 15;

    f32x4 acc[4][4];
    for (int i = 0; i < 4; ++i)
        for (int j = 0; j < 4; ++j) acc[i][j] = (f32x4){0.f, 0.f, 0.f, 0.f};

    for (int kb = 0; kb < K / 32; ++kb) {
        __syncthreads();
        for (int pp = 0; pp < 2; ++pp) {
            int u = t + pp * 256;
            int row = u >> 2, c = u & 3;
            size_t ga = (size_t)(m0 + row) * K + kb * 32 + c * 8;
            size_t gb = (size_t)(n0 + row) * K + kb * 32 + c * 8;
            int ls = row * LDA + c * 8;
            *(bf16x8*)&As_h[ls] = *(const bf16x8*)(Ah + ga);
            *(bf16x8*)&Bs_h[ls] = *(const bf16x8*)(Bth + gb);
            if constexpr (MODE == 0) {
                *(bf16x8*)&As_l[ls] = *(const bf16x8*)(Al + ga);
                *(bf16x8*)&Bs_l[ls] = *(const bf16x8*)(Btl + gb);
            }
        }
        __syncthreads();

        bf16x8 a[4], b[4];
        for (int mi = 0; mi < 4; ++mi)
            a[mi] = *(const bf16x8*)&As_h[(wr * 64 + mi * 16 + l16) * LDA + quad * 8];
        for (int ni = 0; ni < 4; ++ni)
            b[ni] = *(const bf16x8*)&Bs_h[(wc * 64 + ni * 16 + l16) * LDA + quad * 8];
        for (int mi = 0; mi < 4; ++mi)
            for (int ni = 0; ni < 4; ++ni)
                acc[mi][ni] = MFMA(a[mi], b[ni], acc[mi][ni]);
        if constexpr (MODE == 0) {
            bf16x8 al[4], bl[4];
            for (int mi = 0; mi < 4; ++mi)
                al[mi] = *(const bf16x8*)&As_l[(wr * 64 + mi * 16 + l16) * LDA + quad * 8];
            for (int ni = 0; ni < 4; ++ni)
                bl[ni] = *(const bf16x8*)&Bs_l[(wc * 64 + ni * 16 + l16) * LDA + quad * 8];
            for (int mi = 0; mi < 4; ++mi)
                for (int ni = 0; ni < 4; ++ni) {
                    acc[mi][ni] = MFMA(a[mi], bl[ni], acc[mi][ni]);
                    acc[mi][ni] = MFMA(al[mi], b[ni], acc[mi][ni]);
                }
        }
    }

    // LDS-staged epilogue (C/D layout: col=l16, row=quad*4+r)
    for (int p = 0; p < 2; ++p) {
        __syncthreads();
        if (wr == p) {
            for (int mi = 0; mi < 4; ++mi) {
                int rl = mi * 16 + quad * 4;
                for (int ni = 0; ni < 4; ++ni) {
                    int cl = wc * 64 + ni * 16 + l16;
                    for (int r = 0; r < 4; ++r) {
                        float v = acc[mi][ni][r];
                        unsigned pk;
                        if constexpr (MODE == 0) {
                            short hv = f2bf(v);
                            short lv = f2bf(v - bf2f(hv));
                            pk = (unsigned)(unsigned short)hv |
                                 ((unsigned)(unsigned short)lv << 16);
                        } else {
                            union { float f; unsigned u; } cv; cv.f = v; pk = cv.u;
                        }
                        Ep[(rl + r) * 132 + cl] = pk;
                    }
                }
            }
        }
        __syncthreads();

        if constexpr (MODE == 1) {
            for (int j = 0; j < 8; ++j) {
                int cid = t + j * 256;
                int row = cid >> 5, c = cid & 31;
                f32x4 val;
                for (int q = 0; q < 4; ++q) {
                    union { unsigned u; float f; } cv;
                    cv.u = Ep[row * 132 + c * 4 + q];
                    val[q] = cv.f;
                }
                int gr = m0 + p * 64 + row;
                *(f32x4*)&outf[(size_t)gr * 1024 + n0 + c * 4] = val;
            }
        } else if (blockIdx.y < 9) {
            for (int j = 0; j < 4; ++j) {
                int cid = t + j * 256;
                int row = cid >> 4, c = cid & 15;
                bf16x8 hv, lv;
                for (int q = 0; q < 8; ++q) {
                    unsigned w = Ep[row * 132 + c * 8 + q];
                    hv[q] = (short)(w & 0xffffu);
                    lv[q] = (short)(w >> 16);
                }
                int gr = m0 + p * 64 + row;
                int bb = gr >> 11, s = gr & 2047;
                if (blockIdx.y < 8) {
                    size_t base = (((size_t)(bb * 8 + (n0 >> 7))) * 2048 + s) * 128 + c * 8;
                    *(bf16x8*)&qh[base] = hv;
                    *(bf16x8*)&ql[base] = lv;
                } else {
                    size_t base = ((size_t)bb * 2048 + s) * 128 + c * 8;
                    *(bf16x8*)&kh[base] = hv;
                    *(bf16x8*)&kl[base] = lv;
                }
            }
        } else {
            for (int j = 0; j < 4; ++j) {
                int cid = t + j * 256;
                int d = cid >> 3, sc = cid & 7;
                bf16x8 hv;
                for (int q = 0; q < 8; ++q) {
                    unsigned w = Ep[(sc * 8 + q) * 132 + d];
                    hv[q] = (short)(w & 0xffffu);
                }
                int gr0 = m0 + p * 64 + sc * 8;
                int bb = gr0 >> 11, s0 = gr0 & 2047;
                *(bf16x8*)&vt[((size_t)bb * 128 + d) * 2048 + s0] = hv;
            }
        }
    }
}

// ---------------- flash attention (R2) ----------------
// grid (S/128, B*H); 4 waves x 32 query rows (2 m-blocks); BN=64 keys/iter.
// K/V tiles staged via global_load_lds with XOR-swizzled chunks:
//   phys_chunk = logical_chunk ^ (row & 7)   (chunks of 8 shorts = 16 B)
// -> unpadded strides, conflict-free b128 reads, DMA staging (no VGPR trip).
__global__ __launch_bounds__(256, 2) void attn_k(
    const short* __restrict__ qh, const short* __restrict__ ql,
    const short* __restrict__ kh, const short* __restrict__ kl,
    const short* __restrict__ vt, short* __restrict__ ctx) {
    constexpr int S = 2048, D = 128;
    __shared__ short Kh_s[64 * 128];    // swizzled, no pad
    __shared__ short Kl_s[64 * 128];
    __shared__ short Vt_s[128 * 64];    // swizzled, no pad
    __shared__ short P_s[128 * 72];     // per-wave 32-row slices, stride 64+8

    const int bh = blockIdx.y, b = bh >> 3, h = bh & 7;
    const int q0 = blockIdx.x * 128;
    const int t = threadIdx.x, wave = t >> 6, lane = t & 63;
    const int quad = lane >> 4, l16 = lane & 15;
    const int e8 = l16 & 7;             // xor-swizzle key

    // Q fragments (A-layout A[m=l16][k=quad*8+j]), 2 m-blocks x 4 k-chunks
    bf16x8 qfh[2][4], qfl[2][4];
    for (int mb = 0; mb < 2; ++mb) {
        size_t qbase = ((size_t)(b * 8 + h) * S + q0 + wave * 32 + mb * 16 + l16) * D + quad * 8;
        for (int c = 0; c < 4; ++c) {
            qfh[mb][c] = *(const bf16x8*)(qh + qbase + c * 32);
            qfl[mb][c] = *(const bf16x8*)(ql + qbase + c * 32);
        }
    }

    float mrow[2][4], lrow[2][4];
    f32x4 oacc[2][8];
    for (int mb = 0; mb < 2; ++mb) {
        for (int r = 0; r < 4; ++r) { mrow[mb][r] = -INFINITY; lrow[mb][r] = 0.f; }
        for (int oi = 0; oi < 8; ++oi) oacc[mb][oi] = (f32x4){0.f, 0.f, 0.f, 0.f};
    }

    const float scale = 0.08838834764831845f;  // 1/sqrt(128)

    for (int kt = 0; kt < S / 64; ++kt) {
        __syncthreads();  // protect LDS reuse
        // --- stage K hi/lo: 64 rows x 128; wave w stages rows w*16..w*16+15 ---
        {
            int pch = lane & 15;
            for (int i = 0; i < 4; ++i) {
                int rk = wave * 16 + i * 4 + (lane >> 4);
                int j = pch ^ (rk & 7);
                size_t g = ((size_t)b * S + kt * 64 + rk) * D + j * 8;
                int ldsoff = (wave * 16 + i * 4) * 128;  // + lane*16B by HW
                __builtin_amdgcn_global_load_lds(GLB(kh + g), LDS(&Kh_s[ldsoff]), 16, 0, 0);
                __builtin_amdgcn_global_load_lds(GLB(kl + g), LDS(&Kl_s[ldsoff]), 16, 0, 0);
            }
        }
        // --- stage V^T: 128 rows(o) x 64(s); wave w stages rows w*32..w*32+31 ---
        {
            int pch = lane & 7;
            for (int i = 0; i < 4; ++i) {
                int rv = wave * 32 + i * 8 + (lane >> 3);
                int j = pch ^ (rv & 7);
                size_t g = ((size_t)b * D + rv) * S + kt * 64 + j * 8;
                int ldsoff = (wave * 32 + i * 8) * 64;
                __builtin_amdgcn_global_load_lds(GLB(vt + g), LDS(&Vt_s[ldsoff]), 16, 0, 0);
            }
        }
        __syncthreads();

        // --- S = Q K^T (split: hh + lh + hl), 2 m-blocks ---
        f32x4 sacc[2][4];
        for (int mb = 0; mb < 2; ++mb)
            for (int ni = 0; ni < 4; ++ni) sacc[mb][ni] = (f32x4){0.f, 0.f, 0.f, 0.f};
        for (int ni = 0; ni < 4; ++ni) {
            for (int c = 0; c < 4; ++c) {
                int off = (ni * 16 + l16) * 128 + ((c * 4 + quad) ^ e8) * 8;
                bf16x8 kbh = *(const bf16x8*)&Kh_s[off];
                bf16x8 kbl = *(const bf16x8*)&Kl_s[off];
                for (int mb = 0; mb < 2; ++mb) {
                    sacc[mb][ni] = MFMA(qfh[mb][c], kbh, sacc[mb][ni]);
                    sacc[mb][ni] = MFMA(qfl[mb][c], kbh, sacc[mb][ni]);
                    sacc[mb][ni] = MFMA(qfh[mb][c], kbl, sacc[mb][ni]);
                }
            }
        }

        // --- online softmax (rows quad*4+r per m-block) ---
        for (int mb = 0; mb < 2; ++mb) {
            for (int r = 0; r < 4; ++r) {
                float mx = -INFINITY;
                for (int ni = 0; ni < 4; ++ni) {
                    sacc[mb][ni][r] *= scale;
                    mx = fmaxf(mx, sacc[mb][ni][r]);
                }
                for (int off = 8; off; off >>= 1) mx = fmaxf(mx, __shfl_xor(mx, off));
                float mnew = fmaxf(mrow[mb][r], mx);
                float alpha = __expf(mrow[mb][r] - mnew);
                mrow[mb][r] = mnew;
                float rs = 0.f;
                for (int ni = 0; ni < 4; ++ni) {
                    float pv = __expf(sacc[mb][ni][r] - mnew);
                    sacc[mb][ni][r] = pv;
                    rs += pv;
                }
                for (int off = 8; off; off >>= 1) rs += __shfl_xor(rs, off);
                lrow[mb][r] = lrow[mb][r] * alpha + rs;
                for (int oi = 0; oi < 8; ++oi) oacc[mb][oi][r] *= alpha;
            }
            // P -> LDS (C-layout -> A-layout; per-wave slice)
            for (int ni = 0; ni < 4; ++ni)
                for (int r = 0; r < 4; ++r)
                    P_s[(wave * 32 + mb * 16 + quad * 4 + r) * 72 + ni * 16 + l16] =
                        f2bf(sacc[mb][ni][r]);
        }

        // --- O += P @ V ---
        for (int c2 = 0; c2 < 2; ++c2) {
            bf16x8 pa[2];
            for (int mb = 0; mb < 2; ++mb)
                pa[mb] = *(const bf16x8*)&P_s[(wave * 32 + mb * 16 + l16) * 72 + c2 * 32 + quad * 8];
            for (int oi = 0; oi < 8; ++oi) {
                int off = (oi * 16 + l16) * 64 + ((c2 * 4 + quad) ^ e8) * 8;
                bf16x8 vb = *(const bf16x8*)&Vt_s[off];
                for (int mb = 0; mb < 2; ++mb)
                    oacc[mb][oi] = MFMA(pa[mb], vb, oacc[mb][oi]);
            }
        }
    }

    // epilogue: ctx[b][s][h*128+o] bf16
    for (int mb = 0; mb < 2; ++mb) {
        for (int r = 0; r < 4; ++r) {
            float inv = 1.f / lrow[mb][r];
            int s = q0 + wave * 32 + mb * 16 + quad * 4 + r;
            size_t base = ((size_t)b * S + s) * 1024 + h * 128;
            for (int oi = 0; oi < 8; ++oi)
                ctx[base + oi * 16 + l16] = f2bf(oacc[mb][oi][r] * inv);
        }
    }
}

// ---------------- launch ----------------

extern "C" void kernel_launch(void* const* d_in, const int* in_sizes, int n_in,
                              void* d_out, int out_size, void* d_ws, size_t ws_size,
                              hipStream_t stream) {
    const float* x  = (const float*)d_in[0];
    const float* Wq = (const float*)d_in[1];
    const float* Wk = (const float*)d_in[2];
    const float* Wv = (const float*)d_in[3];
    const float* Wo = (const float*)d_in[4];
    float* out = (float*)d_out;

    char* p = (char*)d_ws;
    auto alloc = [&](size_t bytes) { char* r = p; p += bytes; return r; };
    short* xh  = (short*)alloc(16777216);  // x hi    (8192 x 1024)
    short* xl  = (short*)alloc(16777216);  // x lo
    short* wth = (short*)alloc(2621440);   // Wt hi   (1280 x 1024)
    short* wtl = (short*)alloc(2621440);   // Wt lo
    short* wot = (short*)alloc(2097152);   // Wo^T    (1024 x 1024)
    short* qh  = (short*)alloc(16777216);  // Q hi    (B,H,S,D)
    short* ql  = (short*)alloc(16777216);  // Q lo
    short* kh  = (short*)alloc(2097152);   // K hi    (B,S,D)
    short* kl  = (short*)alloc(2097152);   // K lo
    short* vt  = (short*)alloc(2097152);   // V^T     (B,D,S)
    short* ctx = (short*)alloc(16777216);  // ctx     (B,S,H*D)

    split_kernel<<<dim3(2048), dim3(256), 0, stream>>>(x, xh, xl, 8192 * 1024);
    build_wt<<<dim3(1280), dim3(256), 0, stream>>>(Wq, Wk, Wv, wth, wtl);
    build_wot<<<dim3(1024), dim3(256), 0, stream>>>(Wo, wot);
    gemm_k<0><<<dim3(64, 10), dim3(256), 0, stream>>>(xh, xl, wth, wtl,
                                                      qh, ql, kh, kl, vt, nullptr);
    attn_k<<<dim3(16, 32), dim3(256), 0, stream>>>(qh, ql, kh, kl, vt, ctx);
    gemm_k<1><<<dim3(64, 8), dim3(256), 0, stream>>>(ctx, nullptr, wot, nullptr,
                                                     nullptr, nullptr, nullptr, nullptr,
                                                     nullptr, out);
}

// Round 4
// 380.714 us; speedup vs baseline: 1.6786x; 1.0661x over previous
//
#include <hip/hip_runtime.h>
#include <math.h>

// ---------------------------------------------------------------------------
// Attention: B=4, S=2048, E=1024, H=8, O=128 (fp32 in/out)
// Split-bf16 (hi+lo) MFMA for x->QK and QK^T (precision-critical), plain bf16
// for V / PV / ctx@Wo. Flash-attention (no S x S materialize).
// R1: GEMM epilogue staged through LDS -> coalesced stores.
// R2: attn BM=128 (32 q-rows/wave), DMA staging w/ XOR swizzle.
// R4: gemm staging via global_load_lds width=16 (m97 pattern, unpadded);
//     Q pre-scaled by scale*log2e in gemm<0> epilogue -> attn softmax in
//     exp2 domain (native v_exp_f32, no per-exp mul); softmax denominator
//     via MFMA ones-column (removes 32 shfl-swizzles/wave-iter from DS pipe).
// ---------------------------------------------------------------------------

typedef __attribute__((ext_vector_type(8))) short bf16x8;   // 8 bf16 (4 VGPRs)
typedef __attribute__((ext_vector_type(4))) float f32x4;

#define MFMA(a, b, c) __builtin_amdgcn_mfma_f32_16x16x32_bf16((a), (b), (c), 0, 0, 0)
#define GLB(p) ((const __attribute__((address_space(1))) void*)(p))
#define LDS(p) ((__attribute__((address_space(3))) void*)(p))

#if __has_builtin(__builtin_amdgcn_exp2f)
#define EXP2F(x) __builtin_amdgcn_exp2f(x)
#else
#define EXP2F(x) exp2f(x)
#endif

__device__ __forceinline__ short f2bf(float f) {
    union { float f; unsigned u; } v; v.f = f;
    unsigned r = v.u + 0x7fffu + ((v.u >> 16) & 1u);   // RNE
    return (short)(r >> 16);
}
__device__ __forceinline__ float bf2f(short s) {
    union { unsigned u; float f; } v; v.u = ((unsigned)(unsigned short)s) << 16;
    return v.f;
}

// ---------------- prep kernels ----------------

__global__ __launch_bounds__(256) void split_kernel(
    const float* __restrict__ x, short* __restrict__ hi, short* __restrict__ lo, int n) {
    for (int i = blockIdx.x * blockDim.x + threadIdx.x; i < n; i += gridDim.x * blockDim.x) {
        float f = x[i];
        short h = f2bf(f);
        hi[i] = h;
        lo[i] = f2bf(f - bf2f(h));
    }
}

__global__ __launch_bounds__(256) void build_wt(
    const float* __restrict__ Wq, const float* __restrict__ Wk, const float* __restrict__ Wv,
    short* __restrict__ wth, short* __restrict__ wtl) {
    const int total = 1280 * 1024;
    for (int idx = blockIdx.x * blockDim.x + threadIdx.x; idx < total; idx += gridDim.x * blockDim.x) {
        int n = idx >> 10, k = idx & 1023;
        float f;
        if (n < 1024)      f = Wq[((size_t)(n >> 7) * 1024 + k) * 128 + (n & 127)];
        else if (n < 1152) f = Wk[(size_t)k * 128 + (n - 1024)];
        else               f = Wv[(size_t)k * 128 + (n - 1152)];
        short h = f2bf(f);
        wth[idx] = h;
        wtl[idx] = f2bf(f - bf2f(h));
    }
}

__global__ __launch_bounds__(256) void build_wot(
    const float* __restrict__ Wo, short* __restrict__ wot) {
    const int total = 1024 * 1024;
    for (int idx = blockIdx.x * blockDim.x + threadIdx.x; idx < total; idx += gridDim.x * blockDim.x) {
        int e = idx >> 10, k = idx & 1023;
        wot[idx] = f2bf(Wo[(size_t)k * 1024 + e]);
    }
}

// ---------------- GEMM: C(M x N) = A(M x 1024) @ Bt(N x 1024)^T ----------------
// Staging via global_load_lds width=16 into unpadded 128x32 tiles (m97:
// 64 B row stride rotates banks, no swizzle needed).
template <int MODE>
__global__ __launch_bounds__(256, 2) void gemm_k(
    const short* __restrict__ Ah, const short* __restrict__ Al,
    const short* __restrict__ Bth, const short* __restrict__ Btl,
    short* __restrict__ qh, short* __restrict__ ql,
    short* __restrict__ kh, short* __restrict__ kl,
    short* __restrict__ vt, float* __restrict__ outf) {
    constexpr int K = 1024;
    __shared__ short As_h[128 * 32];
    __shared__ short Bs_h[128 * 32];
    __shared__ short As_l[(MODE == 0 ? 128 : 1) * 32];
    __shared__ short Bs_l[(MODE == 0 ? 128 : 1) * 32];
    __shared__ unsigned int Ep[64 * 132];  // epilogue staging

    const int t = threadIdx.x;
    const int m0 = blockIdx.x * 128, n0 = blockIdx.y * 128;
    const int wave = t >> 6, lane = t & 63;
    const int wr = wave >> 1, wc = wave & 1;
    const int quad = lane >> 4, l16 = lane & 15;

    f32x4 acc[4][4];
    for (int i = 0; i < 4; ++i)
        for (int j = 0; j < 4; ++j) acc[i][j] = (f32x4){0.f, 0.f, 0.f, 0.f};

    for (int kb = 0; kb < K / 32; ++kb) {
        __syncthreads();
        // DMA staging: each matrix = 512 slots of 16 B; 8 wave-insts/matrix,
        // 2 per wave. slot -> row = slot>>2, chunk = slot&3 (natural layout).
        for (int i = 0; i < 2; ++i) {
            int slot = (wave * 2 + i) * 64 + lane;
            int row = slot >> 2, ch = slot & 3;
            int ldsoff = (wave * 2 + i) * 512;  // shorts; +lane*16B by HW
            size_t ga = (size_t)(m0 + row) * K + kb * 32 + ch * 8;
            size_t gb = (size_t)(n0 + row) * K + kb * 32 + ch * 8;
            __builtin_amdgcn_global_load_lds(GLB(Ah + ga), LDS(&As_h[ldsoff]), 16, 0, 0);
            __builtin_amdgcn_global_load_lds(GLB(Bth + gb), LDS(&Bs_h[ldsoff]), 16, 0, 0);
            if constexpr (MODE == 0) {
                __builtin_amdgcn_global_load_lds(GLB(Al + ga), LDS(&As_l[ldsoff]), 16, 0, 0);
                __builtin_amdgcn_global_load_lds(GLB(Btl + gb), LDS(&Bs_l[ldsoff]), 16, 0, 0);
            }
        }
        __syncthreads();

        bf16x8 a[4], b[4];
        for (int mi = 0; mi < 4; ++mi)
            a[mi] = *(const bf16x8*)&As_h[(wr * 64 + mi * 16 + l16) * 32 + quad * 8];
        for (int ni = 0; ni < 4; ++ni)
            b[ni] = *(const bf16x8*)&Bs_h[(wc * 64 + ni * 16 + l16) * 32 + quad * 8];
        for (int mi = 0; mi < 4; ++mi)
            for (int ni = 0; ni < 4; ++ni)
                acc[mi][ni] = MFMA(a[mi], b[ni], acc[mi][ni]);
        if constexpr (MODE == 0) {
            bf16x8 al[4], bl[4];
            for (int mi = 0; mi < 4; ++mi)
                al[mi] = *(const bf16x8*)&As_l[(wr * 64 + mi * 16 + l16) * 32 + quad * 8];
            for (int ni = 0; ni < 4; ++ni)
                bl[ni] = *(const bf16x8*)&Bs_l[(wc * 64 + ni * 16 + l16) * 32 + quad * 8];
            for (int mi = 0; mi < 4; ++mi)
                for (int ni = 0; ni < 4; ++ni) {
                    acc[mi][ni] = MFMA(a[mi], bl[ni], acc[mi][ni]);
                    acc[mi][ni] = MFMA(al[mi], b[ni], acc[mi][ni]);
                }
        }
    }

    // LDS-staged epilogue (C/D layout: col=l16, row=quad*4+r)
    // Q columns pre-scaled by (1/sqrt(128))*log2(e): attn softmax runs in
    // exp2 domain with no per-score multiply.
    const float qscale = 0.12753102455195157f;
    for (int p = 0; p < 2; ++p) {
        __syncthreads();
        if (wr == p) {
            for (int mi = 0; mi < 4; ++mi) {
                int rl = mi * 16 + quad * 4;
                for (int ni = 0; ni < 4; ++ni) {
                    int cl = wc * 64 + ni * 16 + l16;
                    for (int r = 0; r < 4; ++r) {
                        float v = acc[mi][ni][r];
                        unsigned pk;
                        if constexpr (MODE == 0) {
                            if (blockIdx.y < 8) v *= qscale;
                            short hv = f2bf(v);
                            short lv = f2bf(v - bf2f(hv));
                            pk = (unsigned)(unsigned short)hv |
                                 ((unsigned)(unsigned short)lv << 16);
                        } else {
                            union { float f; unsigned u; } cv; cv.f = v; pk = cv.u;
                        }
                        Ep[(rl + r) * 132 + cl] = pk;
                    }
                }
            }
        }
        __syncthreads();

        if constexpr (MODE == 1) {
            for (int j = 0; j < 8; ++j) {
                int cid = t + j * 256;
                int row = cid >> 5, c = cid & 31;
                f32x4 val;
                for (int q = 0; q < 4; ++q) {
                    union { unsigned u; float f; } cv;
                    cv.u = Ep[row * 132 + c * 4 + q];
                    val[q] = cv.f;
                }
                int gr = m0 + p * 64 + row;
                *(f32x4*)&outf[(size_t)gr * 1024 + n0 + c * 4] = val;
            }
        } else if (blockIdx.y < 9) {
            for (int j = 0; j < 4; ++j) {
                int cid = t + j * 256;
                int row = cid >> 4, c = cid & 15;
                bf16x8 hv, lv;
                for (int q = 0; q < 8; ++q) {
                    unsigned w = Ep[row * 132 + c * 8 + q];
                    hv[q] = (short)(w & 0xffffu);
                    lv[q] = (short)(w >> 16);
                }
                int gr = m0 + p * 64 + row;
                int bb = gr >> 11, s = gr & 2047;
                if (blockIdx.y < 8) {
                    size_t base = (((size_t)(bb * 8 + (n0 >> 7))) * 2048 + s) * 128 + c * 8;
                    *(bf16x8*)&qh[base] = hv;
                    *(bf16x8*)&ql[base] = lv;
                } else {
                    size_t base = ((size_t)bb * 2048 + s) * 128 + c * 8;
                    *(bf16x8*)&kh[base] = hv;
                    *(bf16x8*)&kl[base] = lv;
                }
            }
        } else {
            for (int j = 0; j < 4; ++j) {
                int cid = t + j * 256;
                int d = cid >> 3, sc = cid & 7;
                bf16x8 hv;
                for (int q = 0; q < 8; ++q) {
                    unsigned w = Ep[(sc * 8 + q) * 132 + d];
                    hv[q] = (short)(w & 0xffffu);
                }
                int gr0 = m0 + p * 64 + sc * 8;
                int bb = gr0 >> 11, s0 = gr0 & 2047;
                *(bf16x8*)&vt[((size_t)bb * 128 + d) * 2048 + s0] = hv;
            }
        }
    }
}

// ---------------- flash attention ----------------
// grid (S/128, B*H); 4 waves x 32 query rows (2 m-blocks); BN=64 keys/iter.
// K/V staged via global_load_lds with XOR-swizzled chunks (256 B rows need
// swizzle; phys_chunk = logical ^ (row & 7)). Softmax in exp2 domain
// (Q pre-scaled); denominator l via MFMA ones-column, rescaled like O.
__global__ __launch_bounds__(256, 2) void attn_k(
    const short* __restrict__ qh, const short* __restrict__ ql,
    const short* __restrict__ kh, const short* __restrict__ kl,
    const short* __restrict__ vt, short* __restrict__ ctx) {
    constexpr int S = 2048, D = 128;
    __shared__ short Kh_s[64 * 128];    // swizzled, no pad
    __shared__ short Kl_s[64 * 128];
    __shared__ short Vt_s[128 * 64];    // swizzled, no pad
    __shared__ short P_s[128 * 72];     // per-wave 32-row slices, stride 64+8

    const int bh = blockIdx.y, b = bh >> 3, h = bh & 7;
    const int q0 = blockIdx.x * 128;
    const int t = threadIdx.x, wave = t >> 6, lane = t & 63;
    const int quad = lane >> 4, l16 = lane & 15;
    const int e8 = l16 & 7;             // xor-swizzle key

    // ones B-fragment: B[n=l16][k] = (n==0) ? 1.0bf16 : 0  -> C[., col0] = rowsum
    bf16x8 bones;
    {
        short o = (l16 == 0) ? (short)0x3F80 : (short)0;
        for (int j = 0; j < 8; ++j) bones[j] = o;
    }

    // Q fragments (A-layout A[m=l16][k=quad*8+j]), 2 m-blocks x 4 k-chunks
    bf16x8 qfh[2][4], qfl[2][4];
    for (int mb = 0; mb < 2; ++mb) {
        size_t qbase = ((size_t)(b * 8 + h) * S + q0 + wave * 32 + mb * 16 + l16) * D + quad * 8;
        for (int c = 0; c < 4; ++c) {
            qfh[mb][c] = *(const bf16x8*)(qh + qbase + c * 32);
            qfl[mb][c] = *(const bf16x8*)(ql + qbase + c * 32);
        }
    }

    float mrow[2][4];
    f32x4 oacc[2][8], lacc[2];
    for (int mb = 0; mb < 2; ++mb) {
        for (int r = 0; r < 4; ++r) mrow[mb][r] = -INFINITY;
        for (int oi = 0; oi < 8; ++oi) oacc[mb][oi] = (f32x4){0.f, 0.f, 0.f, 0.f};
        lacc[mb] = (f32x4){0.f, 0.f, 0.f, 0.f};
    }

    for (int kt = 0; kt < S / 64; ++kt) {
        __syncthreads();  // protect LDS reuse
        // --- stage K hi/lo: 64 rows x 128 ---
        {
            int pch = lane & 15;
            for (int i = 0; i < 4; ++i) {
                int rk = wave * 16 + i * 4 + (lane >> 4);
                int j = pch ^ (rk & 7);
                size_t g = ((size_t)b * S + kt * 64 + rk) * D + j * 8;
                int ldsoff = (wave * 16 + i * 4) * 128;
                __builtin_amdgcn_global_load_lds(GLB(kh + g), LDS(&Kh_s[ldsoff]), 16, 0, 0);
                __builtin_amdgcn_global_load_lds(GLB(kl + g), LDS(&Kl_s[ldsoff]), 16, 0, 0);
            }
        }
        // --- stage V^T: 128 rows(o) x 64(s) ---
        {
            int pch = lane & 7;
            for (int i = 0; i < 4; ++i) {
                int rv = wave * 32 + i * 8 + (lane >> 3);
                int j = pch ^ (rv & 7);
                size_t g = ((size_t)b * D + rv) * S + kt * 64 + j * 8;
                int ldsoff = (wave * 32 + i * 8) * 64;
                __builtin_amdgcn_global_load_lds(GLB(vt + g), LDS(&Vt_s[ldsoff]), 16, 0, 0);
            }
        }
        __syncthreads();

        // --- S' = Q' K^T (split: hh + lh + hl); scores already * scale*log2e ---
        f32x4 sacc[2][4];
        for (int mb = 0; mb < 2; ++mb)
            for (int ni = 0; ni < 4; ++ni) sacc[mb][ni] = (f32x4){0.f, 0.f, 0.f, 0.f};
        for (int ni = 0; ni < 4; ++ni) {
            for (int c = 0; c < 4; ++c) {
                int off = (ni * 16 + l16) * 128 + ((c * 4 + quad) ^ e8) * 8;
                bf16x8 kbh = *(const bf16x8*)&Kh_s[off];
                bf16x8 kbl = *(const bf16x8*)&Kl_s[off];
                for (int mb = 0; mb < 2; ++mb) {
                    sacc[mb][ni] = MFMA(qfh[mb][c], kbh, sacc[mb][ni]);
                    sacc[mb][ni] = MFMA(qfl[mb][c], kbh, sacc[mb][ni]);
                    sacc[mb][ni] = MFMA(qfh[mb][c], kbl, sacc[mb][ni]);
                }
            }
        }

        // --- online softmax (exp2 domain); rows quad*4+r per m-block ---
        for (int mb = 0; mb < 2; ++mb) {
            for (int r = 0; r < 4; ++r) {
                float mx = fmaxf(fmaxf(sacc[mb][0][r], sacc[mb][1][r]),
                                 fmaxf(sacc[mb][2][r], sacc[mb][3][r]));
                for (int off = 8; off; off >>= 1) mx = fmaxf(mx, __shfl_xor(mx, off));
                float mnew = fmaxf(mrow[mb][r], mx);
                float alpha = EXP2F(mrow[mb][r] - mnew);
                mrow[mb][r] = mnew;
                for (int ni = 0; ni < 4; ++ni)
                    sacc[mb][ni][r] = EXP2F(sacc[mb][ni][r] - mnew);
                lacc[mb][r] *= alpha;
                for (int oi = 0; oi < 8; ++oi) oacc[mb][oi][r] *= alpha;
            }
            // P -> LDS (C-layout -> A-layout; per-wave slice)
            for (int ni = 0; ni < 4; ++ni)
                for (int r = 0; r < 4; ++r)
                    P_s[(wave * 32 + mb * 16 + quad * 4 + r) * 72 + ni * 16 + l16] =
                        f2bf(sacc[mb][ni][r]);
        }

        // --- O += P @ V ; l += P @ ones (MFMA) ---
        for (int c2 = 0; c2 < 2; ++c2) {
            bf16x8 pa[2];
            for (int mb = 0; mb < 2; ++mb) {
                pa[mb] = *(const bf16x8*)&P_s[(wave * 32 + mb * 16 + l16) * 72 + c2 * 32 + quad * 8];
                lacc[mb] = MFMA(pa[mb], bones, lacc[mb]);
            }
            for (int oi = 0; oi < 8; ++oi) {
                int off = (oi * 16 + l16) * 64 + ((c2 * 4 + quad) ^ e8) * 8;
                bf16x8 vb = *(const bf16x8*)&Vt_s[off];
                for (int mb = 0; mb < 2; ++mb)
                    oacc[mb][oi] = MFMA(pa[mb], vb, oacc[mb][oi]);
            }
        }
    }

    // epilogue: ctx[b][s][h*128+o] bf16; l lives in col-0 lanes (l16==0)
    for (int mb = 0; mb < 2; ++mb) {
        for (int r = 0; r < 4; ++r) {
            float ls = __shfl(lacc[mb][r], lane & 48);  // broadcast from l16==0 of this quad
            float inv = 1.f / ls;
            int s = q0 + wave * 32 + mb * 16 + quad * 4 + r;
            size_t base = ((size_t)b * S + s) * 1024 + h * 128;
            for (int oi = 0; oi < 8; ++oi)
                ctx[base + oi * 16 + l16] = f2bf(oacc[mb][oi][r] * inv);
        }
    }
}

// ---------------- launch ----------------

extern "C" void kernel_launch(void* const* d_in, const int* in_sizes, int n_in,
                              void* d_out, int out_size, void* d_ws, size_t ws_size,
                              hipStream_t stream) {
    const float* x  = (const float*)d_in[0];
    const float* Wq = (const float*)d_in[1];
    const float* Wk = (const float*)d_in[2];
    const float* Wv = (const float*)d_in[3];
    const float* Wo = (const float*)d_in[4];
    float* out = (float*)d_out;

    char* p = (char*)d_ws;
    auto alloc = [&](size_t bytes) { char* r = p; p += bytes; return r; };
    short* xh  = (short*)alloc(16777216);  // x hi    (8192 x 1024)
    short* xl  = (short*)alloc(16777216);  // x lo
    short* wth = (short*)alloc(2621440);   // Wt hi   (1280 x 1024)
    short* wtl = (short*)alloc(2621440);   // Wt lo
    short* wot = (short*)alloc(2097152);   // Wo^T    (1024 x 1024)
    short* qh  = (short*)alloc(16777216);  // Q hi    (B,H,S,D), pre-scaled
    short* ql  = (short*)alloc(16777216);  // Q lo
    short* kh  = (short*)alloc(2097152);   // K hi    (B,S,D)
    short* kl  = (short*)alloc(2097152);   // K lo
    short* vt  = (short*)alloc(2097152);   // V^T     (B,D,S)
    short* ctx = (short*)alloc(16777216);  // ctx     (B,S,H*D)

    split_kernel<<<dim3(2048), dim3(256), 0, stream>>>(x, xh, xl, 8192 * 1024);
    build_wt<<<dim3(1280), dim3(256), 0, stream>>>(Wq, Wk, Wv, wth, wtl);
    build_wot<<<dim3(1024), dim3(256), 0, stream>>>(Wo, wot);
    gemm_k<0><<<dim3(64, 10), dim3(256), 0, stream>>>(xh, xl, wth, wtl,
                                                      qh, ql, kh, kl, vt, nullptr);
    attn_k<<<dim3(16, 32), dim3(256), 0, stream>>>(qh, ql, kh, kl, vt, ctx);
    gemm_k<1><<<dim3(64, 8), dim3(256), 0, stream>>>(ctx, nullptr, wot, nullptr,
                                                     nullptr, nullptr, nullptr, nullptr,
                                                     nullptr, out);
}